// Round 1
// baseline (4087.568 us; speedup 1.0000x reference)
//
#include <hip/hip_runtime.h>
#include <hip/hip_bf16.h>

// Problem constants
// B=2, L=1024, E=512, H=8, D=64, P=64
// inputs: seq [2,1024,512], pair [2,1024,1024,64], W_qkv [512,1536],
//         W_bias [64,8], W_out [512,512], b_out [512]   (all fp32)
// output: [2,1024,512] fp32

#define LSEQ 1024
#define EMB  512
#define NH   8
#define HD   64

// ---------------------------------------------------------------------------
// Kernel 1: QKV GEMM.  A[2048][512] @ W[512][1536] -> scatter into
//   q  [B][H][L][D]  (scaled by 1/8)
//   kT [B][H][D][L]  (transposed for coalesced attention score loads)
//   v  [B][H][L][D]
// 64x64 tile, 256 threads, 4x4 microtile, K-step 32.
// ---------------------------------------------------------------------------
__global__ __launch_bounds__(256, 2) void gemm_qkv_kernel(
    const float* __restrict__ A, const float* __restrict__ W,
    float* __restrict__ qb, float* __restrict__ ktb, float* __restrict__ vb)
{
    __shared__ float smem[64 * 68];          // As[32][68] + Bs[32][68], reused for epilogue transpose
    float* As = smem;                        // transposed A tile: As[k][m]
    float* Bs = smem + 32 * 68;              // Bs[k][n]

    const int t  = threadIdx.x;
    const int m0 = blockIdx.y * 64;
    const int n0 = blockIdx.x * 64;
    const int tx = t & 15, ty = t >> 4;

    const int am = t >> 2,        ak = (t & 3) * 8;   // A tile: 64 rows x 32 k, 8 elems/thread
    const int bk = t >> 3,        bn = (t & 7) * 8;   // B tile: 32 k x 64 n,  8 elems/thread

    float acc[4][4] = {};

    for (int k0 = 0; k0 < 512; k0 += 32) {
        float4 a0 = *(const float4*)&A[(size_t)(m0 + am) * 512 + k0 + ak];
        float4 a1 = *(const float4*)&A[(size_t)(m0 + am) * 512 + k0 + ak + 4];
        float4 b0 = *(const float4*)&W[(size_t)(k0 + bk) * 1536 + n0 + bn];
        float4 b1 = *(const float4*)&W[(size_t)(k0 + bk) * 1536 + n0 + bn + 4];
        __syncthreads();                     // previous iteration's reads done
        As[(ak + 0) * 68 + am] = a0.x;
        As[(ak + 1) * 68 + am] = a0.y;
        As[(ak + 2) * 68 + am] = a0.z;
        As[(ak + 3) * 68 + am] = a0.w;
        As[(ak + 4) * 68 + am] = a1.x;
        As[(ak + 5) * 68 + am] = a1.y;
        As[(ak + 6) * 68 + am] = a1.z;
        As[(ak + 7) * 68 + am] = a1.w;
        *(float4*)&Bs[bk * 68 + bn]     = b0;
        *(float4*)&Bs[bk * 68 + bn + 4] = b1;
        __syncthreads();
#pragma unroll
        for (int kk = 0; kk < 32; kk++) {
            float4 a4 = *(float4*)&As[kk * 68 + ty * 4];
            float4 b4 = *(float4*)&Bs[kk * 68 + tx * 4];
            float av[4] = {a4.x, a4.y, a4.z, a4.w};
            float bv[4] = {b4.x, b4.y, b4.z, b4.w};
#pragma unroll
            for (int r = 0; r < 4; r++)
#pragma unroll
                for (int c = 0; c < 4; c++) acc[r][c] += av[r] * bv[c];
        }
    }

    const int sect = n0 >> 9;                // 0=q, 1=k, 2=v
    const int h    = (n0 >> 6) & 7;
    const int b    = m0 >> 10;               // tile never crosses batch boundary
    const int i0   = m0 & 1023;

    if (sect == 1) {
        // transpose through LDS, then coalesced stores into kT[b][h][d][i]
        __syncthreads();
        float* T = smem;                     // [64][68] : T[d][m_local]
#pragma unroll
        for (int r = 0; r < 4; r++)
#pragma unroll
            for (int c = 0; c < 4; c++)
                T[(tx * 4 + c) * 68 + (ty * 4 + r)] = acc[r][c];
        __syncthreads();
        const int dp = t >> 2, iq = (t & 3) * 16;
        float* dst = ktb + (((size_t)(b * 8 + h)) * 64 + dp) * 1024 + i0 + iq;
#pragma unroll
        for (int u = 0; u < 4; u++)
            *(float4*)&dst[u * 4] = *(float4*)&T[dp * 68 + iq + u * 4];
    } else {
        float* dst = (sect == 0) ? qb : vb;
        const float sc = (sect == 0) ? 0.125f : 1.0f;   // 1/sqrt(64) folded into q
#pragma unroll
        for (int r = 0; r < 4; r++) {
            const int i = i0 + ty * 4 + r;
#pragma unroll
            for (int c = 0; c < 4; c++) {
                const int d = tx * 4 + c;
                dst[(((size_t)(b * 8 + h)) * 1024 + i) * 64 + d] = acc[r][c] * sc;
            }
        }
    }
}

// ---------------------------------------------------------------------------
// Kernel 2: fused pair-bias flash attention.
// grid = B*L blocks, 512 threads = 8 waves, wave w == head h.
// Per block (b,i): stream j in tiles of 64. pair tile staged once in LDS
// (pad 65 -> conflict-free bias dot). K read via kT (coalesced, stride-L),
// V read [j][d] coalesced. Online softmax per (h,i) row.
// ---------------------------------------------------------------------------
__global__ __launch_bounds__(512, 4) void attn_kernel(
    const float* __restrict__ pair, const float* __restrict__ Wb,
    const float* __restrict__ qb, const float* __restrict__ ktb,
    const float* __restrict__ vb, float* __restrict__ ctx)
{
    __shared__ float plds[64 * 65];          // pair tile [j'][p], padded
    __shared__ float qlds[8 * 64];           // q for all heads of row i (pre-scaled)

    const int t    = threadIdx.x;
    const int lane = t & 63;
    const int h    = t >> 6;
    const int bi   = blockIdx.x;             // b*1024 + i
    const int b    = bi >> 10;
    const int i    = bi & 1023;

    qlds[t] = qb[(((size_t)(b * 8 + h)) * 1024 + i) * 64 + lane];

    float wbr[64];
#pragma unroll
    for (int p = 0; p < 64; p++) wbr[p] = Wb[p * 8 + h];

    float mrun = -3.0e38f, lrun = 0.f, ctxa = 0.f;

    const float* kbase = ktb + ((size_t)(b * 8 + h)) * 64 * 1024 + lane;
    const float* vbase = vb  + (((size_t)(b * 8 + h)) * 1024) * 64 + lane;
    const float* pbase = pair + (size_t)bi * 65536;   // [j][p]

    __syncthreads();

    for (int j0 = 0; j0 < 1024; j0 += 64) {
        // ---- stage pair tile: 4096 floats, 8 per thread, coalesced ----
        {
            const float* src = pbase + j0 * 64;
            float4 f0 = *(const float4*)&src[t * 8];
            float4 f1 = *(const float4*)&src[t * 8 + 4];
            float* dst = &plds[(t >> 3) * 65 + (t & 7) * 8];
            dst[0] = f0.x; dst[1] = f0.y; dst[2] = f0.z; dst[3] = f0.w;
            dst[4] = f1.x; dst[5] = f1.y; dst[6] = f1.z; dst[7] = f1.w;
        }
        __syncthreads();

        // ---- scores: s(lane) for j = j0+lane ----
        float s0 = 0.f, s1 = 0.f, s2 = 0.f, s3 = 0.f;
        const float* kc = kbase + j0;
#pragma unroll
        for (int d = 0; d < 64; d += 4) {
            s0 += qlds[h * 64 + d + 0] * kc[(d + 0) * 1024];
            s1 += qlds[h * 64 + d + 1] * kc[(d + 1) * 1024];
            s2 += qlds[h * 64 + d + 2] * kc[(d + 2) * 1024];
            s3 += qlds[h * 64 + d + 3] * kc[(d + 3) * 1024];
        }
        float s = (s0 + s1) + (s2 + s3);

        float bb0 = 0.f, bb1 = 0.f, bb2 = 0.f, bb3 = 0.f;
#pragma unroll
        for (int p = 0; p < 64; p += 4) {
            bb0 += plds[lane * 65 + p + 0] * wbr[p + 0];
            bb1 += plds[lane * 65 + p + 1] * wbr[p + 1];
            bb2 += plds[lane * 65 + p + 2] * wbr[p + 2];
            bb3 += plds[lane * 65 + p + 3] * wbr[p + 3];
        }
        s += (bb0 + bb1) + (bb2 + bb3);

        // ---- online softmax ----
        float tmax = s;
#pragma unroll
        for (int off = 32; off; off >>= 1) tmax = fmaxf(tmax, __shfl_xor(tmax, off));
        const float mnew = fmaxf(mrun, tmax);
        const float corr = __expf(mrun - mnew);
        const float pv   = __expf(s - mnew);
        float tsum = pv;
#pragma unroll
        for (int off = 32; off; off >>= 1) tsum += __shfl_xor(tsum, off);
        lrun = lrun * corr + tsum;
        mrun = mnew;

        // ---- PV: ctx[d=lane] += sum_j p_j * v[j][lane] ----
        float c0 = 0.f, c1 = 0.f, c2 = 0.f, c3 = 0.f;
        const float* vc = vbase + j0 * 64;
#pragma unroll
        for (int jj = 0; jj < 64; jj += 4) {
            c0 += __shfl(pv, jj + 0) * vc[(jj + 0) * 64];
            c1 += __shfl(pv, jj + 1) * vc[(jj + 1) * 64];
            c2 += __shfl(pv, jj + 2) * vc[(jj + 2) * 64];
            c3 += __shfl(pv, jj + 3) * vc[(jj + 3) * 64];
        }
        ctxa = ctxa * corr + ((c0 + c1) + (c2 + c3));

        __syncthreads();                     // before next pair-tile overwrite
    }

    // ctx stored as [B][L][E] with E = h*64 + d  (ready for out-proj GEMM)
    ctx[(size_t)bi * 512 + h * 64 + lane] = ctxa / lrun;
}

// ---------------------------------------------------------------------------
// Kernel 3: out = ctx[2048][512] @ W_out[512][512] + b_out
// ---------------------------------------------------------------------------
__global__ __launch_bounds__(256, 2) void gemm_out_kernel(
    const float* __restrict__ A, const float* __restrict__ W,
    const float* __restrict__ bias, float* __restrict__ out)
{
    __shared__ float smem[64 * 68];
    float* As = smem;
    float* Bs = smem + 32 * 68;

    const int t  = threadIdx.x;
    const int m0 = blockIdx.y * 64;
    const int n0 = blockIdx.x * 64;
    const int tx = t & 15, ty = t >> 4;

    const int am = t >> 2, ak = (t & 3) * 8;
    const int bk = t >> 3, bn = (t & 7) * 8;

    float acc[4][4] = {};

    for (int k0 = 0; k0 < 512; k0 += 32) {
        float4 a0 = *(const float4*)&A[(size_t)(m0 + am) * 512 + k0 + ak];
        float4 a1 = *(const float4*)&A[(size_t)(m0 + am) * 512 + k0 + ak + 4];
        float4 b0 = *(const float4*)&W[(size_t)(k0 + bk) * 512 + n0 + bn];
        float4 b1 = *(const float4*)&W[(size_t)(k0 + bk) * 512 + n0 + bn + 4];
        __syncthreads();
        As[(ak + 0) * 68 + am] = a0.x;
        As[(ak + 1) * 68 + am] = a0.y;
        As[(ak + 2) * 68 + am] = a0.z;
        As[(ak + 3) * 68 + am] = a0.w;
        As[(ak + 4) * 68 + am] = a1.x;
        As[(ak + 5) * 68 + am] = a1.y;
        As[(ak + 6) * 68 + am] = a1.z;
        As[(ak + 7) * 68 + am] = a1.w;
        *(float4*)&Bs[bk * 68 + bn]     = b0;
        *(float4*)&Bs[bk * 68 + bn + 4] = b1;
        __syncthreads();
#pragma unroll
        for (int kk = 0; kk < 32; kk++) {
            float4 a4 = *(float4*)&As[kk * 68 + ty * 4];
            float4 b4 = *(float4*)&Bs[kk * 68 + tx * 4];
            float av[4] = {a4.x, a4.y, a4.z, a4.w};
            float bv[4] = {b4.x, b4.y, b4.z, b4.w};
#pragma unroll
            for (int r = 0; r < 4; r++)
#pragma unroll
                for (int c = 0; c < 4; c++) acc[r][c] += av[r] * bv[c];
        }
    }

    float4 bo = *(const float4*)&bias[n0 + tx * 4];
    float bv[4] = {bo.x, bo.y, bo.z, bo.w};
#pragma unroll
    for (int r = 0; r < 4; r++) {
        const int m = m0 + ty * 4 + r;
#pragma unroll
        for (int c = 0; c < 4; c++)
            out[(size_t)m * 512 + n0 + tx * 4 + c] = acc[r][c] + bv[c];
    }
}

// ---------------------------------------------------------------------------
extern "C" void kernel_launch(void* const* d_in, const int* in_sizes, int n_in,
                              void* d_out, int out_size, void* d_ws, size_t ws_size,
                              hipStream_t stream)
{
    const float* seq  = (const float*)d_in[0];
    const float* pair = (const float*)d_in[1];
    const float* Wqkv = (const float*)d_in[2];
    const float* Wb   = (const float*)d_in[3];
    const float* Wout = (const float*)d_in[4];
    const float* bout = (const float*)d_in[5];
    float* out = (float*)d_out;

    float* qb  = (float*)d_ws;               // [B][H][L][D]  1M floats
    float* ktb = qb  + (1 << 20);            // [B][H][D][L]  1M floats
    float* vb  = ktb + (1 << 20);            // [B][H][L][D]  1M floats
    float* ctx = vb  + (1 << 20);            // [B][L][E]     1M floats

    gemm_qkv_kernel<<<dim3(24, 32), 256, 0, stream>>>(seq, Wqkv, qb, ktb, vb);
    attn_kernel<<<2048, 512, 0, stream>>>(pair, Wb, qb, ktb, vb, ctx);
    gemm_out_kernel<<<dim3(8, 32), 256, 0, stream>>>(ctx, Wout, bout, out);
}

// Round 2
// 2234.773 us; speedup vs baseline: 1.8291x; 1.8291x over previous
//
#include <hip/hip_runtime.h>
#include <hip/hip_bf16.h>

// B=2, L=1024, E=512, H=8, D=64, P=64
// inputs: seq [2,1024,512], pair [2,1024,1024,64], W_qkv [512,1536],
//         W_bias [64,8], W_out [512,512], b_out [512]   (all fp32)

#define BFLO(u) __uint_as_float((u) << 16)
#define BFHI(u) __uint_as_float((u) & 0xffff0000u)

__device__ __forceinline__ unsigned pk2(float a, float b) {
    __hip_bfloat16 ha = __float2bfloat16(a);
    __hip_bfloat16 hb = __float2bfloat16(b);
    return (unsigned)__bfloat16_as_ushort(ha) | ((unsigned)__bfloat16_as_ushort(hb) << 16);
}

// ---------------------------------------------------------------------------
// Kernel 1: QKV GEMM.  A[2048][512] @ W[512][1536] ->
//   q  [B][H][L][D]  scaled by 1/8
//   k  [B][H][L][D]  plain (row-major per j: per-lane float4 reads in attn)
//   vT [B][H][D][L]  transposed (per-lane float4 PV reads in attn)
// ---------------------------------------------------------------------------
__global__ __launch_bounds__(256, 2) void gemm_qkv_kernel(
    const float* __restrict__ A, const float* __restrict__ W,
    float* __restrict__ qb, float* __restrict__ kb, float* __restrict__ vtb)
{
    __shared__ float smem[64 * 68];
    float* As = smem;                        // As[k][m] (transposed A tile)
    float* Bs = smem + 32 * 68;              // Bs[k][n]

    const int t  = threadIdx.x;
    const int m0 = blockIdx.y * 64;
    const int n0 = blockIdx.x * 64;
    const int tx = t & 15, ty = t >> 4;

    const int am = t >> 2, ak = (t & 3) * 8;
    const int bk = t >> 3, bn = (t & 7) * 8;

    float acc[4][4] = {};

    for (int k0 = 0; k0 < 512; k0 += 32) {
        float4 a0 = *(const float4*)&A[(size_t)(m0 + am) * 512 + k0 + ak];
        float4 a1 = *(const float4*)&A[(size_t)(m0 + am) * 512 + k0 + ak + 4];
        float4 b0 = *(const float4*)&W[(size_t)(k0 + bk) * 1536 + n0 + bn];
        float4 b1 = *(const float4*)&W[(size_t)(k0 + bk) * 1536 + n0 + bn + 4];
        __syncthreads();
        As[(ak + 0) * 68 + am] = a0.x;
        As[(ak + 1) * 68 + am] = a0.y;
        As[(ak + 2) * 68 + am] = a0.z;
        As[(ak + 3) * 68 + am] = a0.w;
        As[(ak + 4) * 68 + am] = a1.x;
        As[(ak + 5) * 68 + am] = a1.y;
        As[(ak + 6) * 68 + am] = a1.z;
        As[(ak + 7) * 68 + am] = a1.w;
        *(float4*)&Bs[bk * 68 + bn]     = b0;
        *(float4*)&Bs[bk * 68 + bn + 4] = b1;
        __syncthreads();
#pragma unroll
        for (int kk = 0; kk < 32; kk++) {
            float4 a4 = *(float4*)&As[kk * 68 + ty * 4];
            float4 b4 = *(float4*)&Bs[kk * 68 + tx * 4];
            float av[4] = {a4.x, a4.y, a4.z, a4.w};
            float bv[4] = {b4.x, b4.y, b4.z, b4.w};
#pragma unroll
            for (int r = 0; r < 4; r++)
#pragma unroll
                for (int c = 0; c < 4; c++) acc[r][c] += av[r] * bv[c];
        }
    }

    const int sect = n0 >> 9;                // 0=q, 1=k, 2=v
    const int h    = (n0 >> 6) & 7;
    const int b    = m0 >> 10;
    const int i0   = m0 & 1023;

    if (sect == 2) {
        // transpose through LDS -> vT[b][h][d][j]
        __syncthreads();
        float* T = smem;                     // [64][68] : T[d][m_local]
#pragma unroll
        for (int r = 0; r < 4; r++)
#pragma unroll
            for (int c = 0; c < 4; c++)
                T[(tx * 4 + c) * 68 + (ty * 4 + r)] = acc[r][c];
        __syncthreads();
        const int dp = t >> 2, iq = (t & 3) * 16;
        float* dst = vtb + (((size_t)(b * 8 + h)) * 64 + dp) * 1024 + i0 + iq;
#pragma unroll
        for (int u = 0; u < 4; u++)
            *(float4*)&dst[u * 4] = *(float4*)&T[dp * 68 + iq + u * 4];
    } else {
        float* dst = (sect == 0) ? qb : kb;
        const float sc = (sect == 0) ? 0.125f : 1.0f;   // 1/sqrt(64) folded into q
#pragma unroll
        for (int r = 0; r < 4; r++) {
            const int i = i0 + ty * 4 + r;
#pragma unroll
            for (int c = 0; c < 4; c++) {
                const int d = tx * 4 + c;
                dst[(((size_t)(b * 8 + h)) * 1024 + i) * 64 + d] = acc[r][c] * sc;
            }
        }
    }
}

// ---------------------------------------------------------------------------
// Kernel 2: fused pair-bias flash attention.
// grid = 512 blocks = (b, i-tile of 4 rows). 512 threads = 8 waves, wave = head.
// Per j-tile of 64: pair slab [4i][64j][64p] staged once as bf16 in LDS
// (XOR-swizzled rows, ds_read_b128); bias dot + QK (per-lane K float4 from
// global, L2-resident) + online softmax + PV (per-lane vT float4).
// Register prefetch of next slab overlaps compute (T14).
// ---------------------------------------------------------------------------
__global__ __launch_bounds__(512, 4) void attn_kernel(
    const float* __restrict__ pair, const float* __restrict__ Wb,
    const float* __restrict__ qb, const float* __restrict__ kb,
    const float* __restrict__ vtb, float* __restrict__ ctx)
{
    __shared__ __align__(16) char  plds[4 * 64 * 128];   // [ii][j] rows, 128B bf16, swizzled
    __shared__ __align__(16) float qlds[4 * 8 * 64];     // [ii][h][d], q pre-scaled
    __shared__ __align__(16) float wlds[8 * 64];         // [h][p]
    __shared__ __align__(16) float pbuf[4 * 8 * 64];     // [ii][h][j]

    const int t    = threadIdx.x;
    const int lane = t & 63;
    const int h    = t >> 6;
    const int bx   = blockIdx.x;
    const int b    = bx >> 8;
    const int i0   = (bx & 255) * 4;

    // one-time loads
    wlds[t] = Wb[(t & 63) * 8 + (t >> 6)];               // wlds[h][p] = Wb[p][h]
    {
        const int base = t * 4;
        const int qi = base >> 9, qh = (base >> 6) & 7, qd = base & 63;
        *(float4*)&qlds[base] =
            *(const float4*)&qb[(((size_t)(b * 8 + qh)) * 1024 + i0 + qi) * 64 + qd];
    }

    // staging geometry: thread t covers (ii = t>>7, j = (t&127)>>1, p0 = (t&1)*32)
    const int sii = t >> 7;
    const int sj  = (t & 127) >> 1;
    const int sp0 = (t & 1) * 32;
    const float* pslab = pair + (((size_t)(b * 1024 + i0 + sii)) * 1024 + sj) * 64 + sp0;
    char* swbase = plds + (size_t)(sii * 64 + sj) * 128;
    const int swx = (sj & 7) << 4;

    // ---- stage tile 0 ----
    {
        float4 pf[8];
#pragma unroll
        for (int u = 0; u < 8; u++) pf[u] = *(const float4*)(pslab + u * 4);
#pragma unroll
        for (int k = 0; k < 4; k++) {
            const int c = (t & 1) * 4 + k;
            uint4 w;
            w.x = pk2(pf[2 * k].x, pf[2 * k].y);
            w.y = pk2(pf[2 * k].z, pf[2 * k].w);
            w.z = pk2(pf[2 * k + 1].x, pf[2 * k + 1].y);
            w.w = pk2(pf[2 * k + 1].z, pf[2 * k + 1].w);
            *(uint4*)(swbase + ((c * 16) ^ swx)) = w;
        }
    }
    __syncthreads();

    float mrun[4], lrun[4], ctxa[4];
#pragma unroll
    for (int ii = 0; ii < 4; ii++) { mrun[ii] = -3.0e38f; lrun[ii] = 0.f; ctxa[ii] = 0.f; }

    const char*  prow  = (const char*)plds + (size_t)lane * 128;
    const int    rswx  = (lane & 7) << 4;
    const float* kbase = kb  + ((size_t)(b * 8 + h) * 1024) * 64;
    const float* vrow0 = vtb + (((size_t)(b * 8 + h)) * 64 + lane) * 1024;

    for (int jt = 0; jt < 16; jt++) {
        // ---- prefetch next slab into regs (overlaps with compute below) ----
        float4 pf[8];
        if (jt < 15) {
            const float* src = pslab + (size_t)(jt + 1) * 64 * 64;
#pragma unroll
            for (int u = 0; u < 8; u++) pf[u] = *(const float4*)(src + u * 4);
        }

        // ---- bias: s[ii](lane=j) = sum_p pair_bf16 * w ----
        float s[4] = {0.f, 0.f, 0.f, 0.f};
#pragma unroll
        for (int c = 0; c < 8; c++) {
            const float4 w0 = *(const float4*)&wlds[h * 64 + c * 8];
            const float4 w1 = *(const float4*)&wlds[h * 64 + c * 8 + 4];
            const int off = (c * 16) ^ rswx;
#pragma unroll
            for (int ii = 0; ii < 4; ii++) {
                const uint4 u = *(const uint4*)(prow + ii * 8192 + off);
                s[ii] += BFLO(u.x) * w0.x + BFHI(u.x) * w0.y
                       + BFLO(u.y) * w0.z + BFHI(u.y) * w0.w
                       + BFLO(u.z) * w1.x + BFHI(u.z) * w1.y
                       + BFLO(u.w) * w1.z + BFHI(u.w) * w1.w;
            }
        }

        // ---- QK: per-lane K row (global, L2), q broadcast from LDS ----
        {
            const float* krow = kbase + (size_t)(jt * 64 + lane) * 64;
#pragma unroll
            for (int c = 0; c < 16; c++) {
                const float4 kk = *(const float4*)&krow[c * 4];
#pragma unroll
                for (int ii = 0; ii < 4; ii++) {
                    const float4 qq = *(const float4*)&qlds[(ii * 8 + h) * 64 + c * 4];
                    s[ii] += qq.x * kk.x + qq.y * kk.y + qq.z * kk.z + qq.w * kk.w;
                }
            }
        }

        // ---- online softmax per ii ----
#pragma unroll
        for (int ii = 0; ii < 4; ii++) {
            float tmax = s[ii];
#pragma unroll
            for (int off = 32; off; off >>= 1) tmax = fmaxf(tmax, __shfl_xor(tmax, off));
            const float mnew = fmaxf(mrun[ii], tmax);
            const float corr = __expf(mrun[ii] - mnew);
            const float pv   = __expf(s[ii] - mnew);
            float ts = pv;
#pragma unroll
            for (int off = 32; off; off >>= 1) ts += __shfl_xor(ts, off);
            lrun[ii] = lrun[ii] * corr + ts;
            mrun[ii] = mnew;
            ctxa[ii] *= corr;
            pbuf[(ii * 8 + h) * 64 + lane] = pv;   // same-wave write, read below
        }

        // ---- PV: lane=d, p broadcast from LDS, vT per-lane float4 ----
        {
            const float* vrow = vrow0 + jt * 64;
#pragma unroll
            for (int c = 0; c < 16; c++) {
                const float4 vv = *(const float4*)&vrow[c * 4];
#pragma unroll
                for (int ii = 0; ii < 4; ii++) {
                    const float4 pp = *(const float4*)&pbuf[(ii * 8 + h) * 64 + c * 4];
                    ctxa[ii] += pp.x * vv.x + pp.y * vv.y + pp.z * vv.z + pp.w * vv.w;
                }
            }
        }

        __syncthreads();                     // all waves done reading plds
        if (jt < 15) {
#pragma unroll
            for (int k = 0; k < 4; k++) {
                const int c = (t & 1) * 4 + k;
                uint4 w;
                w.x = pk2(pf[2 * k].x, pf[2 * k].y);
                w.y = pk2(pf[2 * k].z, pf[2 * k].w);
                w.z = pk2(pf[2 * k + 1].x, pf[2 * k + 1].y);
                w.w = pk2(pf[2 * k + 1].z, pf[2 * k + 1].w);
                *(uint4*)(swbase + ((c * 16) ^ swx)) = w;
            }
        }
        __syncthreads();
    }

    // ctx stored [B][L][E], E = h*64 + d
#pragma unroll
    for (int ii = 0; ii < 4; ii++)
        ctx[((size_t)(b * 1024 + i0 + ii)) * 512 + h * 64 + lane] = ctxa[ii] / lrun[ii];
}

// ---------------------------------------------------------------------------
// Kernel 3: out = ctx[2048][512] @ W_out[512][512] + b_out
// ---------------------------------------------------------------------------
__global__ __launch_bounds__(256, 2) void gemm_out_kernel(
    const float* __restrict__ A, const float* __restrict__ W,
    const float* __restrict__ bias, float* __restrict__ out)
{
    __shared__ float smem[64 * 68];
    float* As = smem;
    float* Bs = smem + 32 * 68;

    const int t  = threadIdx.x;
    const int m0 = blockIdx.y * 64;
    const int n0 = blockIdx.x * 64;
    const int tx = t & 15, ty = t >> 4;

    const int am = t >> 2, ak = (t & 3) * 8;
    const int bk = t >> 3, bn = (t & 7) * 8;

    float acc[4][4] = {};

    for (int k0 = 0; k0 < 512; k0 += 32) {
        float4 a0 = *(const float4*)&A[(size_t)(m0 + am) * 512 + k0 + ak];
        float4 a1 = *(const float4*)&A[(size_t)(m0 + am) * 512 + k0 + ak + 4];
        float4 b0 = *(const float4*)&W[(size_t)(k0 + bk) * 512 + n0 + bn];
        float4 b1 = *(const float4*)&W[(size_t)(k0 + bk) * 512 + n0 + bn + 4];
        __syncthreads();
        As[(ak + 0) * 68 + am] = a0.x;
        As[(ak + 1) * 68 + am] = a0.y;
        As[(ak + 2) * 68 + am] = a0.z;
        As[(ak + 3) * 68 + am] = a0.w;
        As[(ak + 4) * 68 + am] = a1.x;
        As[(ak + 5) * 68 + am] = a1.y;
        As[(ak + 6) * 68 + am] = a1.z;
        As[(ak + 7) * 68 + am] = a1.w;
        *(float4*)&Bs[bk * 68 + bn]     = b0;
        *(float4*)&Bs[bk * 68 + bn + 4] = b1;
        __syncthreads();
#pragma unroll
        for (int kk = 0; kk < 32; kk++) {
            float4 a4 = *(float4*)&As[kk * 68 + ty * 4];
            float4 b4 = *(float4*)&Bs[kk * 68 + tx * 4];
            float av[4] = {a4.x, a4.y, a4.z, a4.w};
            float bv[4] = {b4.x, b4.y, b4.z, b4.w};
#pragma unroll
            for (int r = 0; r < 4; r++)
#pragma unroll
                for (int c = 0; c < 4; c++) acc[r][c] += av[r] * bv[c];
        }
    }

    float4 bo = *(const float4*)&bias[n0 + tx * 4];
    float bv[4] = {bo.x, bo.y, bo.z, bo.w};
#pragma unroll
    for (int r = 0; r < 4; r++) {
        const int m = m0 + ty * 4 + r;
#pragma unroll
        for (int c = 0; c < 4; c++)
            out[(size_t)m * 512 + n0 + tx * 4 + c] = acc[r][c] + bv[c];
    }
}

// ---------------------------------------------------------------------------
extern "C" void kernel_launch(void* const* d_in, const int* in_sizes, int n_in,
                              void* d_out, int out_size, void* d_ws, size_t ws_size,
                              hipStream_t stream)
{
    const float* seq  = (const float*)d_in[0];
    const float* pair = (const float*)d_in[1];
    const float* Wqkv = (const float*)d_in[2];
    const float* Wb   = (const float*)d_in[3];
    const float* Wout = (const float*)d_in[4];
    const float* bout = (const float*)d_in[5];
    float* out = (float*)d_out;

    float* qb  = (float*)d_ws;               // [B][H][L][D]  1M floats
    float* kb  = qb  + (1 << 20);            // [B][H][L][D]  1M floats
    float* vtb = kb  + (1 << 20);            // [B][H][D][L]  1M floats
    float* ctx = vtb + (1 << 20);            // [B][L][E]     1M floats

    gemm_qkv_kernel<<<dim3(24, 32), 256, 0, stream>>>(seq, Wqkv, qb, kb, vtb);
    attn_kernel<<<512, 512, 0, stream>>>(pair, Wb, qb, kb, vtb, ctx);
    gemm_out_kernel<<<dim3(8, 32), 256, 0, stream>>>(ctx, Wout, bout, out);
}

// Round 3
// 440.817 us; speedup vs baseline: 9.2727x; 5.0696x over previous
//
#include <hip/hip_runtime.h>
#include <hip/hip_bf16.h>

// B=2, L=1024, E=512, H=8, D=64, P=64
// inputs: seq [2,1024,512], pair [2,1024,1024,64], W_qkv [512,1536],
//         W_bias [64,8], W_out [512,512], b_out [512]   (all fp32)

#define BFLO(u) __uint_as_float((u) << 16)
#define BFHI(u) __uint_as_float((u) & 0xffff0000u)

__device__ __forceinline__ unsigned pk2(float a, float b) {
    __hip_bfloat16 ha = __float2bfloat16(a);
    __hip_bfloat16 hb = __float2bfloat16(b);
    return (unsigned)__bfloat16_as_ushort(ha) | ((unsigned)__bfloat16_as_ushort(hb) << 16);
}

__device__ __forceinline__ void gl16(const void* g, void* l) {
    __builtin_amdgcn_global_load_lds((const __attribute__((address_space(1))) void*)g,
                                     (__attribute__((address_space(3))) void*)l, 16, 0, 0);
}

// ---------------------------------------------------------------------------
// Kernel 1: QKV GEMM.  A[2048][512] @ W[512][1536] ->
//   q  fp32 [B][H][L][D] scaled by 1/8
//   k  bf16 [B][H][L][D]
//   vT bf16 [B][H][D][L]
// ---------------------------------------------------------------------------
__global__ __launch_bounds__(256, 2) void gemm_qkv_kernel(
    const float* __restrict__ A, const float* __restrict__ W,
    float* __restrict__ qb, unsigned short* __restrict__ kbus,
    unsigned short* __restrict__ vtbus)
{
    __shared__ float smem[64 * 68];
    float* As = smem;                        // As[k][m]
    float* Bs = smem + 32 * 68;              // Bs[k][n]

    const int t  = threadIdx.x;
    const int m0 = blockIdx.y * 64;
    const int n0 = blockIdx.x * 64;
    const int tx = t & 15, ty = t >> 4;

    const int am = t >> 2, ak = (t & 3) * 8;
    const int bk = t >> 3, bn = (t & 7) * 8;

    float acc[4][4] = {};

    for (int k0 = 0; k0 < 512; k0 += 32) {
        float4 a0 = *(const float4*)&A[(size_t)(m0 + am) * 512 + k0 + ak];
        float4 a1 = *(const float4*)&A[(size_t)(m0 + am) * 512 + k0 + ak + 4];
        float4 b0 = *(const float4*)&W[(size_t)(k0 + bk) * 1536 + n0 + bn];
        float4 b1 = *(const float4*)&W[(size_t)(k0 + bk) * 1536 + n0 + bn + 4];
        __syncthreads();
        As[(ak + 0) * 68 + am] = a0.x;
        As[(ak + 1) * 68 + am] = a0.y;
        As[(ak + 2) * 68 + am] = a0.z;
        As[(ak + 3) * 68 + am] = a0.w;
        As[(ak + 4) * 68 + am] = a1.x;
        As[(ak + 5) * 68 + am] = a1.y;
        As[(ak + 6) * 68 + am] = a1.z;
        As[(ak + 7) * 68 + am] = a1.w;
        *(float4*)&Bs[bk * 68 + bn]     = b0;
        *(float4*)&Bs[bk * 68 + bn + 4] = b1;
        __syncthreads();
#pragma unroll
        for (int kk = 0; kk < 32; kk++) {
            float4 a4 = *(float4*)&As[kk * 68 + ty * 4];
            float4 b4 = *(float4*)&Bs[kk * 68 + tx * 4];
            float av[4] = {a4.x, a4.y, a4.z, a4.w};
            float bv[4] = {b4.x, b4.y, b4.z, b4.w};
#pragma unroll
            for (int r = 0; r < 4; r++)
#pragma unroll
                for (int c = 0; c < 4; c++) acc[r][c] += av[r] * bv[c];
        }
    }

    const int sect = n0 >> 9;                // 0=q, 1=k, 2=v
    const int h    = (n0 >> 6) & 7;
    const int b    = m0 >> 10;
    const int i0   = m0 & 1023;

    if (sect == 2) {
        // transpose through LDS -> vT[b][h][d][j] (bf16)
        __syncthreads();
        float* T = smem;                     // [64][68]
#pragma unroll
        for (int r = 0; r < 4; r++)
#pragma unroll
            for (int c = 0; c < 4; c++)
                T[(tx * 4 + c) * 68 + (ty * 4 + r)] = acc[r][c];
        __syncthreads();
        const int dp = t >> 2, iq = (t & 3) * 16;
        unsigned short* dst = vtbus + (((size_t)(b * 8 + h)) * 64 + dp) * 1024 + i0 + iq;
#pragma unroll
        for (int u = 0; u < 4; u++) {
            float4 f = *(float4*)&T[dp * 68 + iq + u * 4];
            uint2 pkd; pkd.x = pk2(f.x, f.y); pkd.y = pk2(f.z, f.w);
            *(uint2*)&dst[u * 4] = pkd;
        }
    } else if (sect == 1) {
        unsigned short* dst = kbus + ((size_t)(b * 8 + h) * 1024) * 64;
#pragma unroll
        for (int r = 0; r < 4; r++) {
            const int i = i0 + ty * 4 + r;
#pragma unroll
            for (int c = 0; c < 4; c += 2) {
                unsigned u = pk2(acc[r][c], acc[r][c + 1]);
                *(unsigned*)&dst[(size_t)i * 64 + tx * 4 + c] = u;
            }
        }
    } else {
        float* dst = qb;
#pragma unroll
        for (int r = 0; r < 4; r++) {
            const int i = i0 + ty * 4 + r;
#pragma unroll
            for (int c = 0; c < 4; c++)
                dst[(((size_t)(b * 8 + h)) * 1024 + i) * 64 + tx * 4 + c] = acc[r][c] * 0.125f;
        }
    }
}

// ---------------------------------------------------------------------------
// Kernel 2: fused pair-bias flash attention.
// 512 blocks = (b, i-tile of 4), 512 threads = 8 waves (wave = head in phase H).
// Pair slab [4ii][64j][64p] fp32 staged via global_load_lds (swizzled source,
// linear LDS dest), double-buffered, raw-barrier 2-phase pipeline.
// Per tile: bias computed ONCE cooperatively -> bias_lds, then per-head
// QK (bf16 K regs) + online softmax + PV (bf16 vT regs).
// ---------------------------------------------------------------------------
__global__ __launch_bounds__(512, 2) void attn_kernel(
    const float* __restrict__ pair, const float* __restrict__ Wb,
    const float* __restrict__ qb, const unsigned short* __restrict__ kbus,
    const unsigned short* __restrict__ vtbus, float* __restrict__ ctx)
{
    __shared__ __align__(16) char  plds[2][65536];   // pair slabs, fp32, swizzled slots
    __shared__ __align__(16) float bias_lds[8 * 256]; // [h][row]  row = ii*64 + j
    __shared__ __align__(16) float qlds[4 * 8 * 64]; // [ii][h][d], pre-scaled
    __shared__ __align__(16) float wlds[8 * 64];     // [h][p]
    __shared__ __align__(16) float pbuf[4 * 8 * 64]; // [ii][h][j]

    const int t    = threadIdx.x;
    const int lane = t & 63;
    const int w    = t >> 6;                 // wave id == head in phase H
    const int bx   = blockIdx.x;
    const int vbid = ((bx & 7) << 6) + (bx >> 3);   // XCD-contiguous (512%8==0)
    const int b    = vbid >> 8;
    const int i0   = (vbid & 255) * 4;

    // one-time LDS init
    wlds[t] = Wb[(t & 63) * 8 + (t >> 6)];           // wlds[h][p] = Wb[p][h]
    {
        const int base = t * 4;
        const int qi = base >> 9, qh = (base >> 6) & 7, qd = base & 63;
        *(float4*)&qlds[base] =
            *(const float4*)&qb[(((size_t)(b * 8 + qh)) * 1024 + i0 + qi) * 64 + qd];
    }

    // staging geometry (global source pre-swizzled, LDS dest linear):
    // round r: LDS off = r*8192 + w*1024 + lane*16
    //   row = r*32 + rowbase,  rowbase = w*4 + (lane>>4)   (ii = r>>1, j = (r&1)*32 + rowbase)
    //   slot_global = (lane&15) ^ (rowbase&15)
    const int rowbase = w * 4 + (lane >> 4);
    const char* pairB = (const char*)pair + (size_t)(b * 1024 + i0) * 262144;
    const char* g00   = pairB + rowbase * 256 + (((lane & 15) ^ (rowbase & 15)) << 4);

#define STAGE(buf, jtn) do {                                                   \
        const char* gg = g00 + (size_t)(jtn) * 16384;                          \
        char* ld = (buf) + (w << 10);                                          \
        _Pragma("unroll")                                                      \
        for (int r = 0; r < 8; r++)                                            \
            gl16(gg + (r >> 1) * 262144 + (r & 1) * 8192, ld + r * 8192);      \
    } while (0)

    // prologue: stage slab 0
    STAGE(plds[0], 0);

    float mrun[4], lrun[4], ctxa[4];
#pragma unroll
    for (int ii = 0; ii < 4; ii++) { mrun[ii] = -3.0e38f; lrun[ii] = 0.f; ctxa[ii] = 0.f; }

    const int hh    = (lane >> 5) * 4;               // bias phase: head group
    const int row_d = w * 32 + (lane & 31);          // bias phase: my row
    const int rx    = (row_d & 15) << 4;

    for (int jt = 0; jt < 16; jt++) {
        const char* cur = plds[jt & 1];

        // ---- B+C: wait own stage loads (and LDS ops), barrier ----
        asm volatile("s_waitcnt vmcnt(0) lgkmcnt(0)" ::: "memory");
        __builtin_amdgcn_sched_barrier(0);
        __builtin_amdgcn_s_barrier();
        __builtin_amdgcn_sched_barrier(0);

        // ---- G: K/V register loads (bf16, L2-resident) ----
        uint4 kr[8], vr[8];
        {
            const unsigned short* krow = kbus + ((size_t)((b * 8 + w) * 1024 + jt * 64 + lane)) * 64;
            const unsigned short* vrow = vtbus + ((size_t)((b * 8 + w) * 64 + lane)) * 1024 + jt * 64;
#pragma unroll
            for (int c = 0; c < 8; c++) kr[c] = *(const uint4*)(krow + c * 8);
#pragma unroll
            for (int c = 0; c < 8; c++) vr[c] = *(const uint4*)(vrow + c * 8);
        }

        // ---- E: issue async stage of next slab ----
        if (jt < 15) STAGE(plds[(jt + 1) & 1], jt + 1);

        // ---- D: cooperative bias (each row read once) ----
        {
            const char* prow = cur + row_d * 256;
            float a0 = 0.f, a1 = 0.f, a2 = 0.f, a3 = 0.f;
#pragma unroll
            for (int c = 0; c < 16; c++) {
                const float4 pr = *(const float4*)(prow + ((c << 4) ^ rx));
                const float4 w0 = *(const float4*)&wlds[(hh + 0) * 64 + c * 4];
                const float4 w1 = *(const float4*)&wlds[(hh + 1) * 64 + c * 4];
                const float4 w2 = *(const float4*)&wlds[(hh + 2) * 64 + c * 4];
                const float4 w3 = *(const float4*)&wlds[(hh + 3) * 64 + c * 4];
                a0 += pr.x * w0.x + pr.y * w0.y + pr.z * w0.z + pr.w * w0.w;
                a1 += pr.x * w1.x + pr.y * w1.y + pr.z * w1.z + pr.w * w1.w;
                a2 += pr.x * w2.x + pr.y * w2.y + pr.z * w2.z + pr.w * w2.w;
                a3 += pr.x * w3.x + pr.y * w3.y + pr.z * w3.z + pr.w * w3.w;
            }
            bias_lds[(hh + 0) * 256 + row_d] = a0;
            bias_lds[(hh + 1) * 256 + row_d] = a1;
            bias_lds[(hh + 2) * 256 + row_d] = a2;
            bias_lds[(hh + 3) * 256 + row_d] = a3;
        }

        // ---- F: bias ready ----
        asm volatile("s_waitcnt lgkmcnt(0)" ::: "memory");
        __builtin_amdgcn_sched_barrier(0);
        __builtin_amdgcn_s_barrier();
        __builtin_amdgcn_sched_barrier(0);

        // ---- H: per-head QK + softmax + PV  (wave w = head) ----
        float s[4];
#pragma unroll
        for (int ii = 0; ii < 4; ii++) s[ii] = bias_lds[w * 256 + ii * 64 + lane];

#pragma unroll
        for (int c = 0; c < 8; c++) {
            const uint4 kk = kr[c];
            const float kf0 = BFLO(kk.x), kf1 = BFHI(kk.x);
            const float kf2 = BFLO(kk.y), kf3 = BFHI(kk.y);
            const float kf4 = BFLO(kk.z), kf5 = BFHI(kk.z);
            const float kf6 = BFLO(kk.w), kf7 = BFHI(kk.w);
#pragma unroll
            for (int ii = 0; ii < 4; ii++) {
                const float4 q0 = *(const float4*)&qlds[(ii * 8 + w) * 64 + c * 8];
                const float4 q1 = *(const float4*)&qlds[(ii * 8 + w) * 64 + c * 8 + 4];
                s[ii] += q0.x * kf0 + q0.y * kf1 + q0.z * kf2 + q0.w * kf3
                       + q1.x * kf4 + q1.y * kf5 + q1.z * kf6 + q1.w * kf7;
            }
        }

#pragma unroll
        for (int ii = 0; ii < 4; ii++) {
            float tmax = s[ii];
#pragma unroll
            for (int off = 32; off; off >>= 1) tmax = fmaxf(tmax, __shfl_xor(tmax, off));
            const float mnew = fmaxf(mrun[ii], tmax);
            const float corr = __expf(mrun[ii] - mnew);
            const float pv   = __expf(s[ii] - mnew);
            float ts = pv;
#pragma unroll
            for (int off = 32; off; off >>= 1) ts += __shfl_xor(ts, off);
            lrun[ii] = lrun[ii] * corr + ts;
            mrun[ii] = mnew;
            ctxa[ii] *= corr;
            pbuf[(ii * 8 + w) * 64 + lane] = pv;     // same-wave write/read
        }

#pragma unroll
        for (int c = 0; c < 8; c++) {
            const uint4 vv = vr[c];
            const float vf0 = BFLO(vv.x), vf1 = BFHI(vv.x);
            const float vf2 = BFLO(vv.y), vf3 = BFHI(vv.y);
            const float vf4 = BFLO(vv.z), vf5 = BFHI(vv.z);
            const float vf6 = BFLO(vv.w), vf7 = BFHI(vv.w);
#pragma unroll
            for (int ii = 0; ii < 4; ii++) {
                const float4 p0 = *(const float4*)&pbuf[(ii * 8 + w) * 64 + c * 8];
                const float4 p1 = *(const float4*)&pbuf[(ii * 8 + w) * 64 + c * 8 + 4];
                ctxa[ii] += p0.x * vf0 + p0.y * vf1 + p0.z * vf2 + p0.w * vf3
                          + p1.x * vf4 + p1.y * vf5 + p1.z * vf6 + p1.w * vf7;
            }
        }
    }

    // ctx stored [B][L][E], E = h*64 + d
#pragma unroll
    for (int ii = 0; ii < 4; ii++)
        ctx[((size_t)(b * 1024 + i0 + ii)) * 512 + w * 64 + lane] = ctxa[ii] / lrun[ii];
#undef STAGE
}

// ---------------------------------------------------------------------------
// Kernel 3: out = ctx[2048][512] @ W_out[512][512] + b_out
// ---------------------------------------------------------------------------
__global__ __launch_bounds__(256, 2) void gemm_out_kernel(
    const float* __restrict__ A, const float* __restrict__ W,
    const float* __restrict__ bias, float* __restrict__ out)
{
    __shared__ float smem[64 * 68];
    float* As = smem;
    float* Bs = smem + 32 * 68;

    const int t  = threadIdx.x;
    const int m0 = blockIdx.y * 64;
    const int n0 = blockIdx.x * 64;
    const int tx = t & 15, ty = t >> 4;

    const int am = t >> 2, ak = (t & 3) * 8;
    const int bk = t >> 3, bn = (t & 7) * 8;

    float acc[4][4] = {};

    for (int k0 = 0; k0 < 512; k0 += 32) {
        float4 a0 = *(const float4*)&A[(size_t)(m0 + am) * 512 + k0 + ak];
        float4 a1 = *(const float4*)&A[(size_t)(m0 + am) * 512 + k0 + ak + 4];
        float4 b0 = *(const float4*)&W[(size_t)(k0 + bk) * 512 + n0 + bn];
        float4 b1 = *(const float4*)&W[(size_t)(k0 + bk) * 512 + n0 + bn + 4];
        __syncthreads();
        As[(ak + 0) * 68 + am] = a0.x;
        As[(ak + 1) * 68 + am] = a0.y;
        As[(ak + 2) * 68 + am] = a0.z;
        As[(ak + 3) * 68 + am] = a0.w;
        As[(ak + 4) * 68 + am] = a1.x;
        As[(ak + 5) * 68 + am] = a1.y;
        As[(ak + 6) * 68 + am] = a1.z;
        As[(ak + 7) * 68 + am] = a1.w;
        *(float4*)&Bs[bk * 68 + bn]     = b0;
        *(float4*)&Bs[bk * 68 + bn + 4] = b1;
        __syncthreads();
#pragma unroll
        for (int kk = 0; kk < 32; kk++) {
            float4 a4 = *(float4*)&As[kk * 68 + ty * 4];
            float4 b4 = *(float4*)&Bs[kk * 68 + tx * 4];
            float av[4] = {a4.x, a4.y, a4.z, a4.w};
            float bv[4] = {b4.x, b4.y, b4.z, b4.w};
#pragma unroll
            for (int r = 0; r < 4; r++)
#pragma unroll
                for (int c = 0; c < 4; c++) acc[r][c] += av[r] * bv[c];
        }
    }

    float4 bo = *(const float4*)&bias[n0 + tx * 4];
    float bv[4] = {bo.x, bo.y, bo.z, bo.w};
#pragma unroll
    for (int r = 0; r < 4; r++) {
        const int m = m0 + ty * 4 + r;
#pragma unroll
        for (int c = 0; c < 4; c++)
            out[(size_t)m * 512 + n0 + tx * 4 + c] = acc[r][c] + bv[c];
    }
}

// ---------------------------------------------------------------------------
extern "C" void kernel_launch(void* const* d_in, const int* in_sizes, int n_in,
                              void* d_out, int out_size, void* d_ws, size_t ws_size,
                              hipStream_t stream)
{
    const float* seq  = (const float*)d_in[0];
    const float* pair = (const float*)d_in[1];
    const float* Wqkv = (const float*)d_in[2];
    const float* Wb   = (const float*)d_in[3];
    const float* Wout = (const float*)d_in[4];
    const float* bout = (const float*)d_in[5];
    float* out = (float*)d_out;

    float*          qb    = (float*)d_ws;                    // fp32 [2][8][1024][64]  4 MB
    unsigned short* kbus  = (unsigned short*)(qb + (1 << 20));   // bf16 [2][8][1024][64]  2 MB
    unsigned short* vtbus = kbus + (1 << 20);                // bf16 [2][8][64][1024]  2 MB
    float*          ctx   = (float*)(vtbus + (1 << 20));     // fp32 [2][1024][512]    4 MB

    gemm_qkv_kernel<<<dim3(24, 32), 256, 0, stream>>>(seq, Wqkv, qb, kbus, vtbus);
    attn_kernel<<<512, 512, 0, stream>>>(pair, Wb, qb, kbus, vtbus, ctx);
    gemm_out_kernel<<<dim3(8, 32), 256, 0, stream>>>(ctx, Wout, bout, out);
}

// Round 4
// 241.564 us; speedup vs baseline: 16.9212x; 1.8248x over previous
//
#include <hip/hip_runtime.h>
#include <hip/hip_bf16.h>

// B=2, L=1024, E=512, H=8, D=64, P=64
// inputs: seq [2,1024,512], pair [2,1024,1024,64], W_qkv [512,1536],
//         W_bias [64,8], W_out [512,512], b_out [512]   (all fp32)

typedef __attribute__((ext_vector_type(8))) short bf16x8;
typedef __attribute__((ext_vector_type(4))) float f32x4;

__device__ __forceinline__ unsigned pk2(float a, float b) {
    __hip_bfloat16 ha = __float2bfloat16(a);
    __hip_bfloat16 hb = __float2bfloat16(b);
    return (unsigned)__bfloat16_as_ushort(ha) | ((unsigned)__bfloat16_as_ushort(hb) << 16);
}

__device__ __forceinline__ void gl16(const void* g, void* l) {
    __builtin_amdgcn_global_load_lds((const __attribute__((address_space(1))) void*)g,
                                     (__attribute__((address_space(3))) void*)l, 16, 0, 0);
}

// ---------------------------------------------------------------------------
// Kernel 1: QKV GEMM.  A[2048][512] @ W[512][1536] ->
//   q  bf16 [B][H][L][D] scaled by 1/8
//   k  bf16 [B][H][L][D]
//   vT bf16 [B][H][D][L]
// ---------------------------------------------------------------------------
__global__ __launch_bounds__(256, 2) void gemm_qkv_kernel(
    const float* __restrict__ A, const float* __restrict__ W,
    unsigned short* __restrict__ qbus, unsigned short* __restrict__ kbus,
    unsigned short* __restrict__ vtbus)
{
    __shared__ float smem[64 * 68];
    float* As = smem;                        // As[k][m]
    float* Bs = smem + 32 * 68;              // Bs[k][n]

    const int t  = threadIdx.x;
    const int m0 = blockIdx.y * 64;
    const int n0 = blockIdx.x * 64;
    const int tx = t & 15, ty = t >> 4;

    const int am = t >> 2, ak = (t & 3) * 8;
    const int bk = t >> 3, bn = (t & 7) * 8;

    float acc[4][4] = {};

    for (int k0 = 0; k0 < 512; k0 += 32) {
        float4 a0 = *(const float4*)&A[(size_t)(m0 + am) * 512 + k0 + ak];
        float4 a1 = *(const float4*)&A[(size_t)(m0 + am) * 512 + k0 + ak + 4];
        float4 b0 = *(const float4*)&W[(size_t)(k0 + bk) * 1536 + n0 + bn];
        float4 b1 = *(const float4*)&W[(size_t)(k0 + bk) * 1536 + n0 + bn + 4];
        __syncthreads();
        As[(ak + 0) * 68 + am] = a0.x;
        As[(ak + 1) * 68 + am] = a0.y;
        As[(ak + 2) * 68 + am] = a0.z;
        As[(ak + 3) * 68 + am] = a0.w;
        As[(ak + 4) * 68 + am] = a1.x;
        As[(ak + 5) * 68 + am] = a1.y;
        As[(ak + 6) * 68 + am] = a1.z;
        As[(ak + 7) * 68 + am] = a1.w;
        *(float4*)&Bs[bk * 68 + bn]     = b0;
        *(float4*)&Bs[bk * 68 + bn + 4] = b1;
        __syncthreads();
#pragma unroll
        for (int kk = 0; kk < 32; kk++) {
            float4 a4 = *(float4*)&As[kk * 68 + ty * 4];
            float4 b4 = *(float4*)&Bs[kk * 68 + tx * 4];
            float av[4] = {a4.x, a4.y, a4.z, a4.w};
            float bv[4] = {b4.x, b4.y, b4.z, b4.w};
#pragma unroll
            for (int r = 0; r < 4; r++)
#pragma unroll
                for (int c = 0; c < 4; c++) acc[r][c] += av[r] * bv[c];
        }
    }

    const int sect = n0 >> 9;                // 0=q, 1=k, 2=v
    const int h    = (n0 >> 6) & 7;
    const int b    = m0 >> 10;
    const int i0   = m0 & 1023;

    if (sect == 2) {
        // transpose through LDS -> vT[b][h][d][j] (bf16)
        __syncthreads();
        float* T = smem;                     // [64][68]
#pragma unroll
        for (int r = 0; r < 4; r++)
#pragma unroll
            for (int c = 0; c < 4; c++)
                T[(tx * 4 + c) * 68 + (ty * 4 + r)] = acc[r][c];
        __syncthreads();
        const int dp = t >> 2, iq = (t & 3) * 16;
        unsigned short* dst = vtbus + (((size_t)(b * 8 + h)) * 64 + dp) * 1024 + i0 + iq;
#pragma unroll
        for (int u = 0; u < 4; u++) {
            float4 f = *(float4*)&T[dp * 68 + iq + u * 4];
            uint2 pkd; pkd.x = pk2(f.x, f.y); pkd.y = pk2(f.z, f.w);
            *(uint2*)&dst[u * 4] = pkd;
        }
    } else {
        unsigned short* dst = (sect == 0) ? qbus : kbus;
        const float sc = (sect == 0) ? 0.125f : 1.0f;   // 1/sqrt(64) folded into q
#pragma unroll
        for (int r = 0; r < 4; r++) {
            const int i = i0 + ty * 4 + r;
#pragma unroll
            for (int c = 0; c < 4; c += 2) {
                unsigned u = pk2(acc[r][c] * sc, acc[r][c + 1] * sc);
                *(unsigned*)&dst[(((size_t)(b * 8 + h)) * 1024 + i) * 64 + tx * 4 + c] = u;
            }
        }
    }
}

// ---------------------------------------------------------------------------
// slab fragment: 8 consecutive fp32 p-values of one slab row -> bf16x8 A-frag
// ---------------------------------------------------------------------------
__device__ __forceinline__ bf16x8 slab_frag(const char* rowb, int ks, int q4, int sw) {
    const int s0 = ks * 8 + q4 * 2;
    const float4 fa = *(const float4*)(rowb + (((s0    ) ^ sw) << 4));
    const float4 fb = *(const float4*)(rowb + (((s0 + 1) ^ sw) << 4));
    uint4 u;
    u.x = pk2(fa.x, fa.y); u.y = pk2(fa.z, fa.w);
    u.z = pk2(fb.x, fb.y); u.w = pk2(fb.z, fb.w);
    return *(bf16x8*)&u;
}

// ---------------------------------------------------------------------------
// Kernel 2: fused pair-bias flash attention, MFMA everywhere.
// grid = 256 blocks = (b, i-tile of 8). 512 threads = 8 waves.
// Per j-tile of 32: slab [8ii][32j][64p] fp32 (64KB) double-buffered via
// global_load_lds (pre-swizzled source). Bias = slab x Wb via MFMA (wave w
// owns ii=w). QK/PV per head (wave=head) via MFMA, M=16 padded (8 valid).
// ---------------------------------------------------------------------------
__global__ __launch_bounds__(512, 2) void attn_kernel(
    const float* __restrict__ pair, const float* __restrict__ Wb,
    const unsigned short* __restrict__ qbus, const unsigned short* __restrict__ kbus,
    const unsigned short* __restrict__ vtbus, float* __restrict__ ctx)
{
    __shared__ __align__(16) char plds[2][65536];            // slab: [256 rows][16 slots]
    __shared__ __align__(16) float bias_lds[8 * 16 * 33];    // [h][i(16, 8-15 zero)][33]
    __shared__ __align__(16) unsigned short pbuf[8 * 16 * 40]; // [h][i16][40]

    const int t    = threadIdx.x;
    const int lane = t & 63;
    const int w    = t >> 6;            // wave id == head (QK/PV) == ii (bias)
    const int q4   = lane >> 4;
    const int l15  = lane & 15;

    const int bx = blockIdx.x;
    const int b  = bx >> 7;
    const int i0 = (bx & 127) * 8;

    // zero bias_lds (pad rows 8..15 stay zero forever)
    for (int z = t; z < 8 * 16 * 33; z += 512) bias_lds[z] = 0.f;

    // W_bias B-fragments (2 k-steps), h = l15 (zero-pad h>=8)
    uint4 wbf[2];
#pragma unroll
    for (int ks = 0; ks < 2; ks++) {
        float f[8];
#pragma unroll
        for (int e = 0; e < 8; e++)
            f[e] = (l15 < 8) ? Wb[(ks * 32 + q4 * 8 + e) * 8 + l15] : 0.f;
        wbf[ks].x = pk2(f[0], f[1]); wbf[ks].y = pk2(f[2], f[3]);
        wbf[ks].z = pk2(f[4], f[5]); wbf[ks].w = pk2(f[6], f[7]);
    }

    // Q A-fragments (2 k-steps): row i = i0 + l15 (pad rows 8-15 = 0)
    uint4 qf[2] = {};
    if (l15 < 8) {
        const unsigned short* qrow = qbus + (size_t)((b * 8 + w) * 1024 + i0 + l15) * 64;
#pragma unroll
        for (int ks = 0; ks < 2; ks++)
            qf[ks] = *(const uint4*)(qrow + ks * 32 + q4 * 8);
    }

    // staging geometry: round r (=ii), wave w, lane: row = r*32 + w*4 + q4,
    // LDS dest (uniform + lane*16) = r*8192 + w*1024 + lane*16,
    // global slot pre-swizzled: l15 ^ (row&15) = l15 ^ ((w*4+q4)&15)
    const int rowbase = w * 4 + q4;
    const char* pairB = (const char*)pair + (size_t)(b * 1024 + i0) * 262144
                      + rowbase * 256 + ((l15 ^ (rowbase & 15)) << 4);
    char* ldsW = (char*)plds + w * 1024;     // wave-uniform LDS base

#define STAGE(bufsel, jtn) do {                                         \
        const char* gg = pairB + (size_t)(jtn) * 8192;                  \
        char* ld = ldsW + (bufsel) * 65536;                             \
        _Pragma("unroll")                                               \
        for (int r = 0; r < 8; r++)                                     \
            gl16(gg + r * 262144, ld + r * 8192);                       \
    } while (0)

    STAGE(0, 0);

    f32x4 acc[4];
#pragma unroll
    for (int dn = 0; dn < 4; dn++) acc[dn] = (f32x4){0.f, 0.f, 0.f, 0.f};
    float mrun[4], lrun[4];
#pragma unroll
    for (int rr = 0; rr < 4; rr++) { mrun[rr] = -3.0e38f; lrun[rr] = 0.f; }

    const unsigned short* kbase = kbus + (size_t)((b * 8 + w) * 1024) * 64;
    const unsigned short* vbase = vtbus + (size_t)((b * 8 + w) * 64) * 1024;

    for (int jt = 0; jt < 32; jt++) {
        // ---- wait own stage, all waves ready ----
        asm volatile("s_waitcnt vmcnt(0) lgkmcnt(0)" ::: "memory");
        __builtin_amdgcn_sched_barrier(0);
        __builtin_amdgcn_s_barrier();
        __builtin_amdgcn_sched_barrier(0);

        const char* cur = (const char*)plds + (jt & 1) * 65536;

        // ---- K/V fragment loads (L2/L3-resident; BEFORE stage issue) ----
        uint4 kf[2][2], vf[4];
        {
            const unsigned short* kt = kbase + (size_t)(jt * 32) * 64;
#pragma unroll
            for (int jn = 0; jn < 2; jn++)
#pragma unroll
                for (int ks = 0; ks < 2; ks++)
                    kf[jn][ks] = *(const uint4*)(kt + (jn * 16 + l15) * 64 + ks * 32 + q4 * 8);
#pragma unroll
            for (int dn = 0; dn < 4; dn++)
                vf[dn] = *(const uint4*)(vbase + (size_t)(dn * 16 + l15) * 1024 + jt * 32 + q4 * 8);
        }

        // ---- issue async stage of next slab ----
        if (jt < 31) STAGE((jt + 1) & 1, jt + 1);

        // ---- bias via MFMA: wave w owns slab rows 32w..32w+31 (ii=w) ----
        {
            const char* rb0 = cur + (32 * w + l15) * 256;        // g=0 rows
            const char* rb1 = cur + (32 * w + 16 + l15) * 256;   // g=1 rows
            f32x4 b0 = {0.f, 0.f, 0.f, 0.f}, b1 = {0.f, 0.f, 0.f, 0.f};
#pragma unroll
            for (int ks = 0; ks < 2; ks++) {
                bf16x8 a0 = slab_frag(rb0, ks, q4, l15);
                b0 = __builtin_amdgcn_mfma_f32_16x16x32_bf16(a0, *(bf16x8*)&wbf[ks], b0, 0, 0, 0);
                bf16x8 a1 = slab_frag(rb1, ks, q4, l15);
                b1 = __builtin_amdgcn_mfma_f32_16x16x32_bf16(a1, *(bf16x8*)&wbf[ks], b1, 0, 0, 0);
            }
            if (l15 < 8) {
                float* bl = &bias_lds[l15 * 528 + w * 33];
#pragma unroll
                for (int rr = 0; rr < 4; rr++) {
                    bl[q4 * 4 + rr]      = b0[rr];   // j = q4*4+rr
                    bl[16 + q4 * 4 + rr] = b1[rr];   // j = 16+q4*4+rr
                }
            }
        }

        // ---- bias visible to all waves ----
        asm volatile("s_waitcnt lgkmcnt(0)" ::: "memory");
        __builtin_amdgcn_sched_barrier(0);
        __builtin_amdgcn_s_barrier();
        __builtin_amdgcn_sched_barrier(0);

        // ---- QK via MFMA, C-init = bias ----
        f32x4 s0, s1;
#pragma unroll
        for (int rr = 0; rr < 4; rr++) {
            s0[rr] = bias_lds[w * 528 + (q4 * 4 + rr) * 33 + l15];
            s1[rr] = bias_lds[w * 528 + (q4 * 4 + rr) * 33 + 16 + l15];
        }
        s0 = __builtin_amdgcn_mfma_f32_16x16x32_bf16(*(bf16x8*)&qf[0], *(bf16x8*)&kf[0][0], s0, 0, 0, 0);
        s0 = __builtin_amdgcn_mfma_f32_16x16x32_bf16(*(bf16x8*)&qf[1], *(bf16x8*)&kf[0][1], s0, 0, 0, 0);
        s1 = __builtin_amdgcn_mfma_f32_16x16x32_bf16(*(bf16x8*)&qf[0], *(bf16x8*)&kf[1][0], s1, 0, 0, 0);
        s1 = __builtin_amdgcn_mfma_f32_16x16x32_bf16(*(bf16x8*)&qf[1], *(bf16x8*)&kf[1][1], s1, 0, 0, 0);

        // ---- online softmax (rows = q4*4+rr; 16-lane row groups) ----
#pragma unroll
        for (int rr = 0; rr < 4; rr++) {
            float x = fmaxf(s0[rr], s1[rr]);
            x = fmaxf(x, __shfl_xor(x, 1));
            x = fmaxf(x, __shfl_xor(x, 2));
            x = fmaxf(x, __shfl_xor(x, 4));
            x = fmaxf(x, __shfl_xor(x, 8));
            const float mnew = fmaxf(mrun[rr], x);
            const float corr = __expf(mrun[rr] - mnew);
            mrun[rr] = mnew;
            const float p0 = __expf(s0[rr] - mnew);
            const float p1 = __expf(s1[rr] - mnew);
            float ts = p0 + p1;
            ts += __shfl_xor(ts, 1);
            ts += __shfl_xor(ts, 2);
            ts += __shfl_xor(ts, 4);
            ts += __shfl_xor(ts, 8);
            lrun[rr] = lrun[rr] * corr + ts;
#pragma unroll
            for (int dn = 0; dn < 4; dn++) acc[dn][rr] *= corr;
            unsigned short* pb = &pbuf[w * 640 + (q4 * 4 + rr) * 40];
            pb[l15]      = __bfloat16_as_ushort(__float2bfloat16(p0));
            pb[16 + l15] = __bfloat16_as_ushort(__float2bfloat16(p1));
        }

        // ---- P writes -> A-frag read (same wave, cross-lane) ----
        asm volatile("s_waitcnt lgkmcnt(0)" ::: "memory");
        __builtin_amdgcn_sched_barrier(0);

        bf16x8 pfrag = *(bf16x8*)&pbuf[w * 640 + l15 * 40 + q4 * 8];
#pragma unroll
        for (int dn = 0; dn < 4; dn++)
            acc[dn] = __builtin_amdgcn_mfma_f32_16x16x32_bf16(pfrag, *(bf16x8*)&vf[dn], acc[dn], 0, 0, 0);
    }

    // ---- epilogue: ctx[b][i][h*64+d], rows i = q4*4+rr (valid q4<2) ----
    if (q4 < 2) {
#pragma unroll
        for (int rr = 0; rr < 4; rr++) {
            const int i = q4 * 4 + rr;
            const float inv = 1.0f / lrun[rr];
            float* crow = ctx + ((size_t)(b * 1024) + i0 + i) * 512 + w * 64;
#pragma unroll
            for (int dn = 0; dn < 4; dn++)
                crow[dn * 16 + l15] = acc[dn][rr] * inv;
        }
    }
#undef STAGE
}

// ---------------------------------------------------------------------------
// Kernel 3: out = ctx[2048][512] @ W_out[512][512] + b_out
// ---------------------------------------------------------------------------
__global__ __launch_bounds__(256, 2) void gemm_out_kernel(
    const float* __restrict__ A, const float* __restrict__ W,
    const float* __restrict__ bias, float* __restrict__ out)
{
    __shared__ float smem[64 * 68];
    float* As = smem;
    float* Bs = smem + 32 * 68;

    const int t  = threadIdx.x;
    const int m0 = blockIdx.y * 64;
    const int n0 = blockIdx.x * 64;
    const int tx = t & 15, ty = t >> 4;

    const int am = t >> 2, ak = (t & 3) * 8;
    const int bk = t >> 3, bn = (t & 7) * 8;

    float acc[4][4] = {};

    for (int k0 = 0; k0 < 512; k0 += 32) {
        float4 a0 = *(const float4*)&A[(size_t)(m0 + am) * 512 + k0 + ak];
        float4 a1 = *(const float4*)&A[(size_t)(m0 + am) * 512 + k0 + ak + 4];
        float4 b0 = *(const float4*)&W[(size_t)(k0 + bk) * 512 + n0 + bn];
        float4 b1 = *(const float4*)&W[(size_t)(k0 + bk) * 512 + n0 + bn + 4];
        __syncthreads();
        As[(ak + 0) * 68 + am] = a0.x;
        As[(ak + 1) * 68 + am] = a0.y;
        As[(ak + 2) * 68 + am] = a0.z;
        As[(ak + 3) * 68 + am] = a0.w;
        As[(ak + 4) * 68 + am] = a1.x;
        As[(ak + 5) * 68 + am] = a1.y;
        As[(ak + 6) * 68 + am] = a1.z;
        As[(ak + 7) * 68 + am] = a1.w;
        *(float4*)&Bs[bk * 68 + bn]     = b0;
        *(float4*)&Bs[bk * 68 + bn + 4] = b1;
        __syncthreads();
#pragma unroll
        for (int kk = 0; kk < 32; kk++) {
            float4 a4 = *(float4*)&As[kk * 68 + ty * 4];
            float4 b4 = *(float4*)&Bs[kk * 68 + tx * 4];
            float av[4] = {a4.x, a4.y, a4.z, a4.w};
            float bv[4] = {b4.x, b4.y, b4.z, b4.w};
#pragma unroll
            for (int r = 0; r < 4; r++)
#pragma unroll
                for (int c = 0; c < 4; c++) acc[r][c] += av[r] * bv[c];
        }
    }

    float4 bo = *(const float4*)&bias[n0 + tx * 4];
    float bv[4] = {bo.x, bo.y, bo.z, bo.w};
#pragma unroll
    for (int r = 0; r < 4; r++) {
        const int m = m0 + ty * 4 + r;
#pragma unroll
        for (int c = 0; c < 4; c++)
            out[(size_t)m * 512 + n0 + tx * 4 + c] = acc[r][c] + bv[c];
    }
}

// ---------------------------------------------------------------------------
extern "C" void kernel_launch(void* const* d_in, const int* in_sizes, int n_in,
                              void* d_out, int out_size, void* d_ws, size_t ws_size,
                              hipStream_t stream)
{
    const float* seq  = (const float*)d_in[0];
    const float* pair = (const float*)d_in[1];
    const float* Wqkv = (const float*)d_in[2];
    const float* Wb   = (const float*)d_in[3];
    const float* Wout = (const float*)d_in[4];
    const float* bout = (const float*)d_in[5];
    float* out = (float*)d_out;

    unsigned short* qbus  = (unsigned short*)d_ws;           // bf16 [2][8][1024][64]  2 MB
    unsigned short* kbus  = qbus + (1 << 20);                // bf16 [2][8][1024][64]  2 MB
    unsigned short* vtbus = kbus + (1 << 20);                // bf16 [2][8][64][1024]  2 MB
    float*          ctx   = (float*)(vtbus + (1 << 20));     // fp32 [2][1024][512]    4 MB

    gemm_qkv_kernel<<<dim3(24, 32), 256, 0, stream>>>(seq, Wqkv, qbus, kbus, vtbus);
    attn_kernel<<<256, 512, 0, stream>>>(pair, Wb, qbus, kbus, vtbus, ctx);
    gemm_out_kernel<<<dim3(8, 32), 256, 0, stream>>>(ctx, Wout, bout, out);
}

// Round 5
// 234.268 us; speedup vs baseline: 17.4483x; 1.0311x over previous
//
#include <hip/hip_runtime.h>
#include <hip/hip_bf16.h>

// B=2, L=1024, E=512, H=8, D=64, P=64
// inputs: seq [2,1024,512], pair [2,1024,1024,64], W_qkv [512,1536],
//         W_bias [64,8], W_out [512,512], b_out [512]   (all fp32)

typedef __attribute__((ext_vector_type(8))) short bf16x8;
typedef __attribute__((ext_vector_type(4))) float f32x4;

__device__ __forceinline__ unsigned pk2(float a, float b) {
    __hip_bfloat16 ha = __float2bfloat16(a);
    __hip_bfloat16 hb = __float2bfloat16(b);
    return (unsigned)__bfloat16_as_ushort(ha) | ((unsigned)__bfloat16_as_ushort(hb) << 16);
}

// nt (non-temporal, evict-first) pair staging: aux=2 keeps the zero-reuse
// 512 MB pair stream from evicting K/V out of L2/L3.
__device__ __forceinline__ void gl16_nt(const void* g, void* l) {
    __builtin_amdgcn_global_load_lds((const __attribute__((address_space(1))) void*)g,
                                     (__attribute__((address_space(3))) void*)l, 16, 0, 2);
}

// ---------------------------------------------------------------------------
// Kernel 1: QKV GEMM.  A[2048][512] @ W[512][1536] ->
//   q  bf16 [B][H][L][D] scaled by 1/8
//   k  bf16 [B][H][L][D]
//   vT bf16 [B][H][D][L]
// ---------------------------------------------------------------------------
__global__ __launch_bounds__(256, 2) void gemm_qkv_kernel(
    const float* __restrict__ A, const float* __restrict__ W,
    unsigned short* __restrict__ qbus, unsigned short* __restrict__ kbus,
    unsigned short* __restrict__ vtbus)
{
    __shared__ float smem[64 * 68];
    float* As = smem;                        // As[k][m]
    float* Bs = smem + 32 * 68;              // Bs[k][n]

    const int t  = threadIdx.x;
    const int m0 = blockIdx.y * 64;
    const int n0 = blockIdx.x * 64;
    const int tx = t & 15, ty = t >> 4;

    const int am = t >> 2, ak = (t & 3) * 8;
    const int bk = t >> 3, bn = (t & 7) * 8;

    float acc[4][4] = {};

    for (int k0 = 0; k0 < 512; k0 += 32) {
        float4 a0 = *(const float4*)&A[(size_t)(m0 + am) * 512 + k0 + ak];
        float4 a1 = *(const float4*)&A[(size_t)(m0 + am) * 512 + k0 + ak + 4];
        float4 b0 = *(const float4*)&W[(size_t)(k0 + bk) * 1536 + n0 + bn];
        float4 b1 = *(const float4*)&W[(size_t)(k0 + bk) * 1536 + n0 + bn + 4];
        __syncthreads();
        As[(ak + 0) * 68 + am] = a0.x;
        As[(ak + 1) * 68 + am] = a0.y;
        As[(ak + 2) * 68 + am] = a0.z;
        As[(ak + 3) * 68 + am] = a0.w;
        As[(ak + 4) * 68 + am] = a1.x;
        As[(ak + 5) * 68 + am] = a1.y;
        As[(ak + 6) * 68 + am] = a1.z;
        As[(ak + 7) * 68 + am] = a1.w;
        *(float4*)&Bs[bk * 68 + bn]     = b0;
        *(float4*)&Bs[bk * 68 + bn + 4] = b1;
        __syncthreads();
#pragma unroll
        for (int kk = 0; kk < 32; kk++) {
            float4 a4 = *(float4*)&As[kk * 68 + ty * 4];
            float4 b4 = *(float4*)&Bs[kk * 68 + tx * 4];
            float av[4] = {a4.x, a4.y, a4.z, a4.w};
            float bv[4] = {b4.x, b4.y, b4.z, b4.w};
#pragma unroll
            for (int r = 0; r < 4; r++)
#pragma unroll
                for (int c = 0; c < 4; c++) acc[r][c] += av[r] * bv[c];
        }
    }

    const int sect = n0 >> 9;                // 0=q, 1=k, 2=v
    const int h    = (n0 >> 6) & 7;
    const int b    = m0 >> 10;
    const int i0   = m0 & 1023;

    if (sect == 2) {
        // transpose through LDS -> vT[b][h][d][j] (bf16)
        __syncthreads();
        float* T = smem;                     // [64][68]
#pragma unroll
        for (int r = 0; r < 4; r++)
#pragma unroll
            for (int c = 0; c < 4; c++)
                T[(tx * 4 + c) * 68 + (ty * 4 + r)] = acc[r][c];
        __syncthreads();
        const int dp = t >> 2, iq = (t & 3) * 16;
        unsigned short* dst = vtbus + (((size_t)(b * 8 + h)) * 64 + dp) * 1024 + i0 + iq;
#pragma unroll
        for (int u = 0; u < 4; u++) {
            float4 f = *(float4*)&T[dp * 68 + iq + u * 4];
            uint2 pkd; pkd.x = pk2(f.x, f.y); pkd.y = pk2(f.z, f.w);
            *(uint2*)&dst[u * 4] = pkd;
        }
    } else {
        unsigned short* dst = (sect == 0) ? qbus : kbus;
        const float sc = (sect == 0) ? 0.125f : 1.0f;   // 1/sqrt(64) folded into q
#pragma unroll
        for (int r = 0; r < 4; r++) {
            const int i = i0 + ty * 4 + r;
#pragma unroll
            for (int c = 0; c < 4; c += 2) {
                unsigned u = pk2(acc[r][c] * sc, acc[r][c + 1] * sc);
                *(unsigned*)&dst[(((size_t)(b * 8 + h)) * 1024 + i) * 64 + tx * 4 + c] = u;
            }
        }
    }
}

// ---------------------------------------------------------------------------
// slab fragment: 8 consecutive fp32 p-values of one slab row -> bf16x8 A-frag
// ---------------------------------------------------------------------------
__device__ __forceinline__ bf16x8 slab_frag(const char* rowb, int ks, int q4, int sw) {
    const int s0 = ks * 8 + q4 * 2;
    const float4 fa = *(const float4*)(rowb + (((s0    ) ^ sw) << 4));
    const float4 fb = *(const float4*)(rowb + (((s0 + 1) ^ sw) << 4));
    uint4 u;
    u.x = pk2(fa.x, fa.y); u.y = pk2(fa.z, fa.w);
    u.z = pk2(fb.x, fb.y); u.w = pk2(fb.z, fb.w);
    return *(bf16x8*)&u;
}

// ---------------------------------------------------------------------------
// Kernel 2: fused pair-bias flash attention, MFMA everywhere.
// grid = 256 blocks = (b, i-tile of 8), XCD-swizzled so each XCD owns 32
// contiguous blocks of ONE batch -> per-XCD K/V working set 2 MB, L2-resident
// (pair stream staged nt so it can't evict K/V).
// Per j-tile of 32: slab [8ii][32j][64p] fp32 (64KB) double-buffered via
// global_load_lds (pre-swizzled source). Bias = slab x Wb via MFMA (wave w
// owns ii=w). QK/PV per head (wave=head) via MFMA, M=16 padded (8 valid).
// ---------------------------------------------------------------------------
__global__ __launch_bounds__(512, 2) void attn_kernel(
    const float* __restrict__ pair, const float* __restrict__ Wb,
    const unsigned short* __restrict__ qbus, const unsigned short* __restrict__ kbus,
    const unsigned short* __restrict__ vtbus, float* __restrict__ ctx)
{
    __shared__ __align__(16) char plds[2][65536];            // slab: [256 rows][16 slots]
    __shared__ __align__(16) float bias_lds[8 * 16 * 33];    // [h][i(16, 8-15 zero)][33]
    __shared__ __align__(16) unsigned short pbuf[8 * 16 * 40]; // [h][i16][40]

    const int t    = threadIdx.x;
    const int lane = t & 63;
    const int w    = t >> 6;            // wave id == head (QK/PV) == ii (bias)
    const int q4   = lane >> 4;
    const int l15  = lane & 15;

    // XCD-aware mapping: default dispatch round-robins bx across the 8 XCDs.
    // vbid = (bx&7)*32 + bx>>3 gives XCD x the contiguous range [32x, 32x+32)
    // -> one batch per XCD half-group, K/V L2-resident.
    const int bx   = blockIdx.x;
    const int vbid = (bx & 7) * 32 + (bx >> 3);
    const int b    = vbid >> 7;
    const int i0   = (vbid & 127) * 8;

    // zero bias_lds (pad rows 8..15 stay zero forever)
    for (int z = t; z < 8 * 16 * 33; z += 512) bias_lds[z] = 0.f;

    // W_bias B-fragments (2 k-steps), h = l15 (zero-pad h>=8)
    uint4 wbf[2];
#pragma unroll
    for (int ks = 0; ks < 2; ks++) {
        float f[8];
#pragma unroll
        for (int e = 0; e < 8; e++)
            f[e] = (l15 < 8) ? Wb[(ks * 32 + q4 * 8 + e) * 8 + l15] : 0.f;
        wbf[ks].x = pk2(f[0], f[1]); wbf[ks].y = pk2(f[2], f[3]);
        wbf[ks].z = pk2(f[4], f[5]); wbf[ks].w = pk2(f[6], f[7]);
    }

    // Q A-fragments (2 k-steps): row i = i0 + l15 (pad rows 8-15 = 0)
    uint4 qf[2] = {};
    if (l15 < 8) {
        const unsigned short* qrow = qbus + (size_t)((b * 8 + w) * 1024 + i0 + l15) * 64;
#pragma unroll
        for (int ks = 0; ks < 2; ks++)
            qf[ks] = *(const uint4*)(qrow + ks * 32 + q4 * 8);
    }

    // staging geometry: round r (=ii), wave w, lane: row = r*32 + w*4 + q4,
    // LDS dest (uniform + lane*16) = r*8192 + w*1024 + lane*16,
    // global slot pre-swizzled: l15 ^ (row&15) = l15 ^ ((w*4+q4)&15)
    const int rowbase = w * 4 + q4;
    const char* pairB = (const char*)pair + (size_t)(b * 1024 + i0) * 262144
                      + rowbase * 256 + ((l15 ^ (rowbase & 15)) << 4);
    char* ldsW = (char*)plds + w * 1024;     // wave-uniform LDS base

#define STAGE(bufsel, jtn) do {                                         \
        const char* gg = pairB + (size_t)(jtn) * 8192;                  \
        char* ld = ldsW + (bufsel) * 65536;                             \
        _Pragma("unroll")                                               \
        for (int r = 0; r < 8; r++)                                     \
            gl16_nt(gg + r * 262144, ld + r * 8192);                    \
    } while (0)

    STAGE(0, 0);

    f32x4 acc[4];
#pragma unroll
    for (int dn = 0; dn < 4; dn++) acc[dn] = (f32x4){0.f, 0.f, 0.f, 0.f};
    float mrun[4], lrun[4];
#pragma unroll
    for (int rr = 0; rr < 4; rr++) { mrun[rr] = -3.0e38f; lrun[rr] = 0.f; }

    const unsigned short* kbase = kbus + (size_t)((b * 8 + w) * 1024) * 64;
    const unsigned short* vbase = vtbus + (size_t)((b * 8 + w) * 64) * 1024;

    for (int jt = 0; jt < 32; jt++) {
        // ---- wait own stage, all waves ready ----
        asm volatile("s_waitcnt vmcnt(0) lgkmcnt(0)" ::: "memory");
        __builtin_amdgcn_sched_barrier(0);
        __builtin_amdgcn_s_barrier();
        __builtin_amdgcn_sched_barrier(0);

        const char* cur = (const char*)plds + (jt & 1) * 65536;

        // ---- K/V fragment loads (L2-resident; BEFORE stage issue) ----
        uint4 kf[2][2], vf[4];
        {
            const unsigned short* kt = kbase + (size_t)(jt * 32) * 64;
#pragma unroll
            for (int jn = 0; jn < 2; jn++)
#pragma unroll
                for (int ks = 0; ks < 2; ks++)
                    kf[jn][ks] = *(const uint4*)(kt + (jn * 16 + l15) * 64 + ks * 32 + q4 * 8);
#pragma unroll
            for (int dn = 0; dn < 4; dn++)
                vf[dn] = *(const uint4*)(vbase + (size_t)(dn * 16 + l15) * 1024 + jt * 32 + q4 * 8);
        }

        // ---- issue async stage of next slab ----
        if (jt < 31) STAGE((jt + 1) & 1, jt + 1);

        // ---- bias via MFMA: wave w owns slab rows 32w..32w+31 (ii=w) ----
        {
            const char* rb0 = cur + (32 * w + l15) * 256;        // g=0 rows
            const char* rb1 = cur + (32 * w + 16 + l15) * 256;   // g=1 rows
            f32x4 b0 = {0.f, 0.f, 0.f, 0.f}, b1 = {0.f, 0.f, 0.f, 0.f};
#pragma unroll
            for (int ks = 0; ks < 2; ks++) {
                bf16x8 a0 = slab_frag(rb0, ks, q4, l15);
                b0 = __builtin_amdgcn_mfma_f32_16x16x32_bf16(a0, *(bf16x8*)&wbf[ks], b0, 0, 0, 0);
                bf16x8 a1 = slab_frag(rb1, ks, q4, l15);
                b1 = __builtin_amdgcn_mfma_f32_16x16x32_bf16(a1, *(bf16x8*)&wbf[ks], b1, 0, 0, 0);
            }
            if (l15 < 8) {
                float* bl = &bias_lds[l15 * 528 + w * 33];
#pragma unroll
                for (int rr = 0; rr < 4; rr++) {
                    bl[q4 * 4 + rr]      = b0[rr];   // j = q4*4+rr
                    bl[16 + q4 * 4 + rr] = b1[rr];   // j = 16+q4*4+rr
                }
            }
        }

        // ---- bias visible to all waves ----
        asm volatile("s_waitcnt lgkmcnt(0)" ::: "memory");
        __builtin_amdgcn_sched_barrier(0);
        __builtin_amdgcn_s_barrier();
        __builtin_amdgcn_sched_barrier(0);

        // ---- QK via MFMA, C-init = bias ----
        f32x4 s0, s1;
#pragma unroll
        for (int rr = 0; rr < 4; rr++) {
            s0[rr] = bias_lds[w * 528 + (q4 * 4 + rr) * 33 + l15];
            s1[rr] = bias_lds[w * 528 + (q4 * 4 + rr) * 33 + 16 + l15];
        }
        s0 = __builtin_amdgcn_mfma_f32_16x16x32_bf16(*(bf16x8*)&qf[0], *(bf16x8*)&kf[0][0], s0, 0, 0, 0);
        s0 = __builtin_amdgcn_mfma_f32_16x16x32_bf16(*(bf16x8*)&qf[1], *(bf16x8*)&kf[0][1], s0, 0, 0, 0);
        s1 = __builtin_amdgcn_mfma_f32_16x16x32_bf16(*(bf16x8*)&qf[0], *(bf16x8*)&kf[1][0], s1, 0, 0, 0);
        s1 = __builtin_amdgcn_mfma_f32_16x16x32_bf16(*(bf16x8*)&qf[1], *(bf16x8*)&kf[1][1], s1, 0, 0, 0);

        // ---- online softmax (rows = q4*4+rr; 16-lane row groups) ----
#pragma unroll
        for (int rr = 0; rr < 4; rr++) {
            float x = fmaxf(s0[rr], s1[rr]);
            x = fmaxf(x, __shfl_xor(x, 1));
            x = fmaxf(x, __shfl_xor(x, 2));
            x = fmaxf(x, __shfl_xor(x, 4));
            x = fmaxf(x, __shfl_xor(x, 8));
            const float mnew = fmaxf(mrun[rr], x);
            const float corr = __expf(mrun[rr] - mnew);
            mrun[rr] = mnew;
            const float p0 = __expf(s0[rr] - mnew);
            const float p1 = __expf(s1[rr] - mnew);
            float ts = p0 + p1;
            ts += __shfl_xor(ts, 1);
            ts += __shfl_xor(ts, 2);
            ts += __shfl_xor(ts, 4);
            ts += __shfl_xor(ts, 8);
            lrun[rr] = lrun[rr] * corr + ts;
#pragma unroll
            for (int dn = 0; dn < 4; dn++) acc[dn][rr] *= corr;
            unsigned short* pb = &pbuf[w * 640 + (q4 * 4 + rr) * 40];
            pb[l15]      = __bfloat16_as_ushort(__float2bfloat16(p0));
            pb[16 + l15] = __bfloat16_as_ushort(__float2bfloat16(p1));
        }

        // ---- P writes -> A-frag read (same wave, cross-lane) ----
        asm volatile("s_waitcnt lgkmcnt(0)" ::: "memory");
        __builtin_amdgcn_sched_barrier(0);

        bf16x8 pfrag = *(bf16x8*)&pbuf[w * 640 + l15 * 40 + q4 * 8];
#pragma unroll
        for (int dn = 0; dn < 4; dn++)
            acc[dn] = __builtin_amdgcn_mfma_f32_16x16x32_bf16(pfrag, *(bf16x8*)&vf[dn], acc[dn], 0, 0, 0);
    }

    // ---- epilogue: ctx[b][i][h*64+d], rows i = q4*4+rr (valid q4<2) ----
    if (q4 < 2) {
#pragma unroll
        for (int rr = 0; rr < 4; rr++) {
            const int i = q4 * 4 + rr;
            const float inv = 1.0f / lrun[rr];
            float* crow = ctx + ((size_t)(b * 1024) + i0 + i) * 512 + w * 64;
#pragma unroll
            for (int dn = 0; dn < 4; dn++)
                crow[dn * 16 + l15] = acc[dn][rr] * inv;
        }
    }
#undef STAGE
}

// ---------------------------------------------------------------------------
// Kernel 3: out = ctx[2048][512] @ W_out[512][512] + b_out
// ---------------------------------------------------------------------------
__global__ __launch_bounds__(256, 2) void gemm_out_kernel(
    const float* __restrict__ A, const float* __restrict__ W,
    const float* __restrict__ bias, float* __restrict__ out)
{
    __shared__ float smem[64 * 68];
    float* As = smem;
    float* Bs = smem + 32 * 68;

    const int t  = threadIdx.x;
    const int m0 = blockIdx.y * 64;
    const int n0 = blockIdx.x * 64;
    const int tx = t & 15, ty = t >> 4;

    const int am = t >> 2, ak = (t & 3) * 8;
    const int bk = t >> 3, bn = (t & 7) * 8;

    float acc[4][4] = {};

    for (int k0 = 0; k0 < 512; k0 += 32) {
        float4 a0 = *(const float4*)&A[(size_t)(m0 + am) * 512 + k0 + ak];
        float4 a1 = *(const float4*)&A[(size_t)(m0 + am) * 512 + k0 + ak + 4];
        float4 b0 = *(const float4*)&W[(size_t)(k0 + bk) * 512 + n0 + bn];
        float4 b1 = *(const float4*)&W[(size_t)(k0 + bk) * 512 + n0 + bn + 4];
        __syncthreads();
        As[(ak + 0) * 68 + am] = a0.x;
        As[(ak + 1) * 68 + am] = a0.y;
        As[(ak + 2) * 68 + am] = a0.z;
        As[(ak + 3) * 68 + am] = a0.w;
        As[(ak + 4) * 68 + am] = a1.x;
        As[(ak + 5) * 68 + am] = a1.y;
        As[(ak + 6) * 68 + am] = a1.z;
        As[(ak + 7) * 68 + am] = a1.w;
        *(float4*)&Bs[bk * 68 + bn]     = b0;
        *(float4*)&Bs[bk * 68 + bn + 4] = b1;
        __syncthreads();
#pragma unroll
        for (int kk = 0; kk < 32; kk++) {
            float4 a4 = *(float4*)&As[kk * 68 + ty * 4];
            float4 b4 = *(float4*)&Bs[kk * 68 + tx * 4];
            float av[4] = {a4.x, a4.y, a4.z, a4.w};
            float bv[4] = {b4.x, b4.y, b4.z, b4.w};
#pragma unroll
            for (int r = 0; r < 4; r++)
#pragma unroll
                for (int c = 0; c < 4; c++) acc[r][c] += av[r] * bv[c];
        }
    }

    float4 bo = *(const float4*)&bias[n0 + tx * 4];
    float bv[4] = {bo.x, bo.y, bo.z, bo.w};
#pragma unroll
    for (int r = 0; r < 4; r++) {
        const int m = m0 + ty * 4 + r;
#pragma unroll
        for (int c = 0; c < 4; c++)
            out[(size_t)m * 512 + n0 + tx * 4 + c] = acc[r][c] + bv[c];
    }
}

// ---------------------------------------------------------------------------
extern "C" void kernel_launch(void* const* d_in, const int* in_sizes, int n_in,
                              void* d_out, int out_size, void* d_ws, size_t ws_size,
                              hipStream_t stream)
{
    const float* seq  = (const float*)d_in[0];
    const float* pair = (const float*)d_in[1];
    const float* Wqkv = (const float*)d_in[2];
    const float* Wb   = (const float*)d_in[3];
    const float* Wout = (const float*)d_in[4];
    const float* bout = (const float*)d_in[5];
    float* out = (float*)d_out;

    unsigned short* qbus  = (unsigned short*)d_ws;           // bf16 [2][8][1024][64]  2 MB
    unsigned short* kbus  = qbus + (1 << 20);                // bf16 [2][8][1024][64]  2 MB
    unsigned short* vtbus = kbus + (1 << 20);                // bf16 [2][8][64][1024]  2 MB
    float*          ctx   = (float*)(vtbus + (1 << 20));     // fp32 [2][1024][512]    4 MB

    gemm_qkv_kernel<<<dim3(24, 32), 256, 0, stream>>>(seq, Wqkv, qbus, kbus, vtbus);
    attn_kernel<<<256, 512, 0, stream>>>(pair, Wb, qbus, kbus, vtbus, ctx);
    gemm_out_kernel<<<dim3(8, 32), 256, 0, stream>>>(ctx, Wout, bout, out);
}